// Round 7
// baseline (229.085 us; speedup 1.0000x reference)
//
#include <hip/hip_runtime.h>
#include <math.h>

#define NN 50000
#define NE 800000
#define IN_CH 64
#define HEADS 8
#define OC 16
#define HID 128
#define NG 500
#define GB2 ((NN + 63) / 64)        // 782 MFMA-GEMM blocks (64-node tiles)
#define SB 3125                     // scatter blocks: 3125*256 == NE exactly, 1 edge/thread
#define NGRP 8                      // XCD-private CSR groups
#define SLOTG 8                     // slots per node per group (deg/XCD ~ Po(2))
#define OVS 64                      // overflow slots per node (device-scope path)
#define XP 72                       // xb LDS pitch (bf16)
#define WP 72                       // wt LDS pitch (bf16)
#define AGB 2048                    // k_agg blocks (multiple of 8 for XCD swizzle)

typedef float v2f __attribute__((ext_vector_type(2)));
typedef _Float16 h2 __attribute__((ext_vector_type(2)));
typedef __attribute__((ext_vector_type(8))) short frag8;   // 8 bf16 (4 VGPRs)
typedef __attribute__((ext_vector_type(4))) float f32x4;   // MFMA C/D

// round-to-nearest-even f32 -> bf16 (as ushort in low bits) — MFMA input path
__device__ __forceinline__ unsigned bf16rn(float f) {
    unsigned u = __float_as_uint(f);
    return (u + 0x7fffu + ((u >> 16) & 1u)) >> 16;
}

// Sum across the 8-lane head group using DPP (VALU pipe, no LDS).
__device__ __forceinline__ float dpp8_sum(float x) {
    int t;
    t = __builtin_amdgcn_update_dpp(0, __float_as_int(x), 0xB1, 0xF, 0xF, true);  // quad_perm [1,0,3,2]
    x += __int_as_float(t);
    t = __builtin_amdgcn_update_dpp(0, __float_as_int(x), 0x4E, 0xF, 0xF, true);  // quad_perm [2,3,0,1]
    x += __int_as_float(t);
    t = __builtin_amdgcn_update_dpp(0, __float_as_int(x), 0x141, 0xF, 0xF, true); // row_half_mirror
    x += __int_as_float(t);
    return x;
}

// v_dot2_f32_f16: 2-ch dot with f32 accumulate (1 inst). Guarded fallback.
#if __has_builtin(__builtin_amdgcn_fdot2)
#define FDOT2(a, b) __builtin_amdgcn_fdot2((a), (b), 0.0f, false)
#else
__device__ __forceinline__ float FDOT2(h2 a, h2 b) {
    v2f af = __builtin_convertvector(a, v2f);
    v2f bf = __builtin_convertvector(b, v2f);
    return af.x * bf.x + af.y * bf.y;
}
#endif

// per-edge math in packed f16 (pk_add/pk_mul/pk_max + v_dot2_f32_f16).
__device__ __forceinline__ void edge_term(unsigned vv, h2 xrnh, h2 a2h,
                                          float& den, v2f& acc2, bool pred) {
    const h2 xvh = __builtin_bit_cast(h2, vv);
    const h2 t2 = xvh + xrnh;                                   // v_pk_add_f16
    const h2 e2 = __builtin_elementwise_max(t2, t2 * (_Float16)0.2f); // pk_mul+pk_max
    const float q = dpp8_sum(FDOT2(e2, a2h));
    const float w = __expf(q);
    if (pred) {
        den += w;
        const v2f xvf = __builtin_convertvector(xvh, v2f);
        acc2 += w * xvf;                                        // v_pk_fma_f32
    }
}

// ---- pre-transpose W -> bf16 [mtx][c][k] once (96 blocks, ~2us) ------------
__global__ __launch_bounds__(256) void k_prep(
    const float* __restrict__ Wl, const float* __restrict__ Wr,
    const float* __restrict__ Wres, unsigned short* __restrict__ Wt)
{
    const int i = blockIdx.x * 256 + threadIdx.x;   // 0..24575
    if (i >= 3 * 64 * HID) return;
    const int m = i >> 13;                           // matrix
    const int r = i & 8191;
    const int k = r >> 7;                            // 0..63
    const int c = r & 127;                           // 0..127 (coalesced reads)
    const float* W = (m == 0) ? Wl : (m == 1) ? Wr : Wres;
    Wt[(size_t)m * 8192 + c * 64 + k] = (unsigned short)bf16rn(W[k * HID + c]);
}

// ---- scatter-only CSR build (runs before the GEMM) ------------------------
// XCD-private groups via real XCC_ID (R22); workgroup-scope atomic executes
// in this XCD's L2; overflow -> device-scope spill (always correct).
__global__ __launch_bounds__(256) void k_scat(
    const int* __restrict__ ei,
    int* __restrict__ cnt,                 // [NGRP+1][NN] (last = overflow, device scope)
    unsigned short* __restrict__ col_src,  // [NGRP][NN][SLOTG]
    unsigned short* __restrict__ ov)       // [NN][OVS]
{
    const int e = blockIdx.x * 256 + threadIdx.x;
    if (e >= NE) return;
    const int s = ei[e];
    const int d = ei[NE + e];
    if ((unsigned)d >= NN) return;                 // defensive
    int xcc;
    asm volatile("s_getreg_b32 %0, hwreg(HW_REG_XCC_ID)" : "=s"(xcc));
    const int g = xcc & (NGRP - 1);
    const int pos = __hip_atomic_fetch_add(&cnt[(size_t)g * NN + d], 1,
                                           __ATOMIC_RELAXED,
                                           __HIP_MEMORY_SCOPE_WORKGROUP);
    if (pos < SLOTG) {
        col_src[((size_t)g * NN + d) * SLOTG + pos] = (unsigned short)s;
    } else {
        const int po = atomicAdd(&cnt[(size_t)NGRP * NN + d], 1);  // device scope
        if (po < OVS)
            ov[(size_t)d * OVS + po] = (unsigned short)s;
    }
}

// ---------------- MFMA GEMM only (782 blocks, pure streaming) --------------
__global__ __launch_bounds__(256) void k_work(
    const float* __restrict__ x,
    const unsigned short* __restrict__ Wt,
    const float* __restrict__ bl, const float* __restrict__ br,
    unsigned short* __restrict__ xlh, unsigned short* __restrict__ xrh,
    unsigned short* __restrict__ xresh)
{
    const int tid = threadIdx.x;
    __shared__ short xb[64 * XP];      // [node][k] bf16
    __shared__ short wt[128 * WP];     // [col][k] bf16 (W transposed)
    const int n0 = blockIdx.x * 64;

    // stage xb: 64 nodes x 64 k, fp32->bf16
#pragma unroll
    for (int i = 0; i < 4; ++i) {
        const int idx = i * 256 + tid;           // 0..1023 float4s
        const int r = idx >> 4;
        const int j4 = idx & 15;
        float4 v = make_float4(0.f, 0.f, 0.f, 0.f);
        if (n0 + r < NN) v = *(const float4*)(x + (size_t)(n0 + r) * IN_CH + j4 * 4);
        uint2 pk;
        pk.x = bf16rn(v.x) | (bf16rn(v.y) << 16);
        pk.y = bf16rn(v.z) | (bf16rn(v.w) << 16);
        *(uint2*)(xb + r * XP + j4 * 4) = pk;
    }

    const int wv = tid >> 6;           // wave 0..3 -> node subtile
    const int lane = tid & 63;
    const int quad = lane >> 4;
    const int mr = lane & 15;
    const int m0 = wv * 16;

    for (int mtx = 0; mtx < 3; ++mtx) {
        const unsigned short* __restrict__ Wtm = Wt + (size_t)mtx * 8192;  // [c][k] bf16
        unsigned short* __restrict__ outp = (mtx == 0) ? xlh : (mtx == 1) ? xrh : xresh;

        __syncthreads();   // xb staged (mtx=0) / previous wt consumed (mtx>0)
#pragma unroll
        for (int i = 0; i < 4; ++i) {
            const int idx = i * 256 + tid;       // 0..1023 16B chunks
            const int c = idx >> 3;              // 0..127
            const int k0 = (idx & 7) * 8;        // 0..56
            const uint4 v = *(const uint4*)(Wtm + c * 64 + k0);
            *(uint4*)(wt + c * WP + k0) = v;
        }
        __syncthreads();

        const frag8 a0 = *(const frag8*)(xb + (m0 + mr) * XP + quad * 8);
        const frag8 a1 = *(const frag8*)(xb + (m0 + mr) * XP + 32 + quad * 8);

#pragma unroll
        for (int nt = 0; nt < 8; ++nt) {
            const int c = nt * 16 + mr;          // this lane's global column
            const frag8 b0 = *(const frag8*)(wt + c * WP + quad * 8);
            const frag8 b1 = *(const frag8*)(wt + c * WP + 32 + quad * 8);
            f32x4 acc = {0.f, 0.f, 0.f, 0.f};
            acc = __builtin_amdgcn_mfma_f32_16x16x32_bf16(a0, b0, acc, 0, 0, 0);
            acc = __builtin_amdgcn_mfma_f32_16x16x32_bf16(a1, b1, acc, 0, 0, 0);

            const float bv = (mtx == 0) ? bl[c] : (mtx == 1) ? br[c] : 0.f;
            const int node_base = n0 + m0 + quad * 4;
#pragma unroll
            for (int r = 0; r < 4; ++r) {
                const int node = node_base + r;
                if (node < NN) {
                    const _Float16 hv = (_Float16)(acc[r] + bv);   // v_cvt_f16_f32
                    outp[(size_t)node * HID + c] = __builtin_bit_cast(unsigned short, hv);
                }
            }
        }
    }
}

// ---- Fused attention: single-pass softmax-aggregate, packed-f16 payload ----
// R27: (a) tail readlane index CLAMPED to 0 for u >= cn — before, the 8-wide
// unrolled tail gathered ~200K garbage rows (predication only gated the
// accumulate, not the load): ~50 MB of junk FETCH. Clamped lanes re-read an
// L1-hot row; results still discarded -> bit-identical. (b) contiguous
// per-wave node ranges + XCD-chunked block swizzle: consecutive nodes share
// cnt lines (16/line) and col_src lines (4/line); strided assignment had
// every metadata line fetched by up to 8 XCDs' L2s.
__global__ __launch_bounds__(256) void k_agg(
    const unsigned short* __restrict__ xlh, const unsigned short* __restrict__ xrh,
    const unsigned short* __restrict__ xresh,
    const int* __restrict__ cnt, const unsigned short* __restrict__ col_src,
    const unsigned short* __restrict__ ov,
    const float* __restrict__ att, const float* __restrict__ bias,
    float* __restrict__ hfeat)
{
    const int lane = threadIdx.x & 63;
    // XCD-chunked bijective swizzle (AGB % 8 == 0): XCD k gets a contiguous
    // chunk of wave ids -> contiguous node range -> metadata single-XCD.
    const int bid = blockIdx.x;
    const int swzb = (bid & 7) * (AGB / 8) + (bid >> 3);
    const int wid = __builtin_amdgcn_readfirstlane((swzb * (int)blockDim.x + (int)threadIdx.x) >> 6);
    const int nw = (AGB * 256) >> 6;                  // 8192 waves
    const int q = NN / nw;                            // 6
    const int r = NN % nw;                            // 848
    const int nbeg = wid * q + (wid < r ? wid : r);
    const int nend = nbeg + q + (wid < r ? 1 : 0);

    const int c0 = lane * 2;
    const int hh = lane >> 3;
    const int ci = (lane & 7) * 2;
    const int grp = lane >> 3;          // this lane's CSR group
    const int gsl = lane & 7;           // slot within group
    h2 a2h;  a2h.x = (_Float16)att[hh * OC + ci];  a2h.y = (_Float16)att[hh * OC + ci + 1];
    v2f b2;  b2.x = bias[c0];           b2.y = bias[c0 + 1];

    // prime the pipeline: setup loads for the first node
    int cgA = 0, covA = 0, slotA = 0;
    unsigned vvrA = 0, vvnA = 0, vvsA = 0;
    if (nbeg < nend) {
        cgA   = cnt[(size_t)grp * NN + nbeg];
        covA  = cnt[(size_t)NGRP * NN + nbeg];
        slotA = (int)col_src[((size_t)grp * NN + nbeg) * SLOTG + gsl];
        vvrA  = *((const unsigned*)(xrh   + (size_t)nbeg * HID) + lane);
        vvnA  = *((const unsigned*)(xlh   + (size_t)nbeg * HID) + lane);
        vvsA  = *((const unsigned*)(xresh + (size_t)nbeg * HID) + lane);
    }

    for (int n = nbeg; n < nend; ++n) {
        // ---- prefetch next node's setup (hidden under this node's work) ----
        const int n2 = n + 1;
        int cgB = 0, covB = 0, slotB = 0;
        unsigned vvrB = 0, vvnB = 0, vvsB = 0;
        if (n2 < nend) {
            cgB   = cnt[(size_t)grp * NN + n2];
            covB  = cnt[(size_t)NGRP * NN + n2];
            slotB = (int)col_src[((size_t)grp * NN + n2) * SLOTG + gsl];
            vvrB  = *((const unsigned*)(xrh   + (size_t)n2 * HID) + lane);
            vvnB  = *((const unsigned*)(xlh   + (size_t)n2 * HID) + lane);
            vvsB  = *((const unsigned*)(xresh + (size_t)n2 * HID) + lane);
        }

        // ---- process node n (setup values arrived last iteration) ----
        const int cg = min(max(cgA, 0), SLOTG);           // defensive
        const int cov = min(max(covA, 0), OVS);
        const bool valid = gsl < cg;
        const unsigned long long mv = __ballot(valid);
        const int cn = __popcll(mv);
        const int pv = __popcll(mv & ((1ull << lane) - 1ull));
        const int dst = valid ? pv : (cn + (lane - pv));
        int sidx = __builtin_amdgcn_ds_permute(dst << 2, slotA);
        if ((unsigned)sidx >= NN) sidx = 0;               // bound all gathers

        const int nfull = cn >> 3;      // wave-uniform
        unsigned vvA[8], vvB[8];
        if (nfull > 0) {                // issue batch 0 FIRST (hide under self-loop)
#pragma unroll
            for (int u = 0; u < 8; ++u) {
                const int s = __builtin_amdgcn_readlane(sidx, u);
                vvA[u] = *((const unsigned*)(xlh + (size_t)s * HID) + lane);
            }
        }

        // self-loop term (overlaps batch-0 gather latency)
        const h2 xrnh = __builtin_bit_cast(h2, vvrA);
        const h2 xlnh = __builtin_bit_cast(h2, vvnA);
        const h2 s2 = xlnh + xrnh;
        const h2 l2 = __builtin_elementwise_max(s2, s2 * (_Float16)0.2f);
        const float qs = dpp8_sum(FDOT2(l2, a2h));
        float den = __expf(qs);
        v2f acc2 = den * __builtin_convertvector(xlnh, v2f);

        int b = 0;
        for (; b + 2 <= nfull; b += 2) {
#pragma unroll
            for (int u = 0; u < 8; ++u) {      // prefetch batch b+1
                const int s = __builtin_amdgcn_readlane(sidx, (b + 1) * 8 + u);
                vvB[u] = *((const unsigned*)(xlh + (size_t)s * HID) + lane);
            }
#pragma unroll
            for (int u = 0; u < 8; ++u) edge_term(vvA[u], xrnh, a2h, den, acc2, true);
            if (b + 2 < nfull) {
#pragma unroll
                for (int u = 0; u < 8; ++u) {  // prefetch batch b+2
                    const int s = __builtin_amdgcn_readlane(sidx, (b + 2) * 8 + u);
                    vvA[u] = *((const unsigned*)(xlh + (size_t)s * HID) + lane);
                }
            }
#pragma unroll
            for (int u = 0; u < 8; ++u) edge_term(vvB[u], xrnh, a2h, den, acc2, true);
        }
        if (b < nfull) {                       // odd final full batch (already loaded)
#pragma unroll
            for (int u = 0; u < 8; ++u) edge_term(vvA[u], xrnh, a2h, den, acc2, true);
        }
        const int j = nfull * 8;
        if (j < cn) {                          // predicated tail batch
#pragma unroll
            for (int u = 0; u < 8; ++u) {
                // R27: clamp OOB slots to slot 0 (uniform index) — junk lanes
                // re-read an L1-hot row instead of fetching a random one.
                const int si = (j + u < cn) ? (j + u) : 0;
                const int s = __builtin_amdgcn_readlane(sidx, si);
                vvA[u] = *((const unsigned*)(xlh + (size_t)s * HID) + lane);
            }
#pragma unroll
            for (int u = 0; u < 8; ++u) edge_term(vvA[u], xrnh, a2h, den, acc2, j + u < cn);
        }
        // overflow edges (rare): broadcast one at a time
        for (int k = 0; k < cov; ++k) {
            int s = (int)ov[(size_t)n * OVS + k];
            if ((unsigned)s >= NN) s = 0;
            const unsigned vvv = *((const unsigned*)(xlh + (size_t)s * HID) + lane);
            edge_term(vvv, xrnh, a2h, den, acc2, true);
        }

        const v2f xrs2 = __builtin_convertvector(__builtin_bit_cast(h2, vvsA), v2f);
        const float inv = 1.f / den;
        v2f t = acc2 * inv + xrs2 + b2;
        float2 st; st.x = t.x; st.y = t.y;
        *(float2*)(hfeat + (size_t)n * HID + c0) = st;

        // rotate pipeline state
        cgA = cgB; covA = covB; slotA = slotB;
        vvrA = vvrB; vvnA = vvnB; vvsA = vvsB;
    }
}

// ---- Fused tail: per-graph {Wlin+ELU pool} + MLP ---------------------------
__global__ __launch_bounds__(256) void k_tail(
    const float* __restrict__ hfeat, const int* __restrict__ batch,
    const float* __restrict__ Wlin, const float* __restrict__ blin,
    const float* __restrict__ W1, const float* __restrict__ b1,
    const float* __restrict__ W2, const float* __restrict__ b2,
    const float* __restrict__ W3, const float* __restrict__ b3,
    float* __restrict__ out)
{
    __shared__ float sWlin[HID * 16];
    __shared__ float sblin[16];
    __shared__ float sW1[256], sb1[16], sW2[512], sb2[32], sW3[160], sb3[5];
    __shared__ float red[256][17];
    __shared__ float sg[16], sv1[16], sv2[32];
    const int g = blockIdx.x;
    const int tid = threadIdx.x;

    for (int i = tid; i < HID * 16; i += 256) sWlin[i] = Wlin[i];
    if (tid < 16)  sblin[tid] = blin[tid];
    if (tid < 256) sW1[tid] = W1[tid];
    for (int i = tid; i < 512; i += 256) sW2[i] = W2[i];
    if (tid < 160) sW3[tid] = W3[tid];
    if (tid < 16)  sb1[tid] = b1[tid];
    if (tid < 32)  sb2[tid] = b2[tid];
    if (tid < 5)   sb3[tid] = b3[tid];
    __syncthreads();

    int lo = 0, hi = NN;
    while (lo < hi) { int mid = (lo + hi) >> 1; if (batch[mid] < g) lo = mid + 1; else hi = mid; }
    int lo2 = lo, hi2 = NN;
    while (lo2 < hi2) { int mid = (lo2 + hi2) >> 1; if (batch[mid] < g + 1) lo2 = mid + 1; else hi2 = mid; }
    const int nbeg = lo, nend = lo2;

    float sum16[16];
#pragma unroll
    for (int j = 0; j < 16; ++j) sum16[j] = 0.f;

    for (int n = nbeg + tid; n < nend; n += 256) {
        float acc[16];
#pragma unroll
        for (int j = 0; j < 16; ++j) acc[j] = sblin[j];
        const float4* hrow = (const float4*)(hfeat + (size_t)n * HID);
#pragma unroll 8
        for (int kc = 0; kc < 32; ++kc) {
            const float4 v = hrow[kc];
#pragma unroll
            for (int j = 0; j < 16; ++j) {
                acc[j] += v.x * sWlin[(kc * 4 + 0) * 16 + j] + v.y * sWlin[(kc * 4 + 1) * 16 + j]
                        + v.z * sWlin[(kc * 4 + 2) * 16 + j] + v.w * sWlin[(kc * 4 + 3) * 16 + j];
            }
        }
#pragma unroll
        for (int j = 0; j < 16; ++j) {
            float o = acc[j];
            o = o > 0.f ? o : __expf(o) - 1.f;
            sum16[j] += o;
        }
    }

#pragma unroll
    for (int j = 0; j < 16; ++j) red[tid][j] = sum16[j];
    __syncthreads();
    for (int s = 128; s > 0; s >>= 1) {
        if (tid < s) {
#pragma unroll
            for (int j = 0; j < 16; ++j) red[tid][j] += red[tid + s][j];
        }
        __syncthreads();
    }

    if (tid < 16) sg[tid] = red[0][tid] / fmaxf((float)(nend - nbeg), 1.f);
    __syncthreads();
    if (tid < 16) {
        float s = sb1[tid];
#pragma unroll
        for (int c = 0; c < 16; ++c) s += sg[c] * sW1[c * 16 + tid];
        sv1[tid] = fmaxf(s, 0.f);
    }
    __syncthreads();
    if (tid < 32) {
        float s = sb2[tid];
#pragma unroll
        for (int c = 0; c < 16; ++c) s += sv1[c] * sW2[c * 32 + tid];
        sv2[tid] = fmaxf(s, 0.f);
    }
    __syncthreads();
    if (tid < 5) {
        float s = sb3[tid];
#pragma unroll
        for (int c = 0; c < 32; ++c) s += sv2[c] * sW3[c * 5 + tid];
        out[g * 5 + tid] = s;
    }
}

extern "C" void kernel_launch(void* const* d_in, const int* in_sizes, int n_in,
                              void* d_out, int out_size, void* d_ws, size_t ws_size,
                              hipStream_t stream)
{
    const float* x    = (const float*)d_in[0];
    const int*   ei   = (const int*)d_in[1];
    const int*   batch= (const int*)d_in[2];
    const float* Wl   = (const float*)d_in[3];
    const float* bl   = (const float*)d_in[4];
    const float* Wr   = (const float*)d_in[5];
    const float* br   = (const float*)d_in[6];
    const float* att  = (const float*)d_in[7];
    const float* Wres = (const float*)d_in[8];
    const float* bias = (const float*)d_in[9];
    const float* Wlin = (const float*)d_in[10];
    const float* blin = (const float*)d_in[11];
    const float* W1   = (const float*)d_in[12];
    const float* b1   = (const float*)d_in[13];
    const float* W2   = (const float*)d_in[14];
    const float* b2   = (const float*)d_in[15];
    const float* W3   = (const float*)d_in[16];
    const float* b3   = (const float*)d_in[17];
    float* out = (float*)d_out;

    uintptr_t p = (uintptr_t)d_ws;
    unsigned short* xlh   = (unsigned short*)p; p += (size_t)NN * HID * 2;
    unsigned short* xrh   = (unsigned short*)p; p += (size_t)NN * HID * 2;
    unsigned short* xresh = (unsigned short*)p; p += (size_t)NN * HID * 2;
    p = (p + 15) & ~(uintptr_t)15;
    float* hfeat  = (float*)p; p += (size_t)NN * HID * 4;
    int* cnt      = (int*)p;   p += (size_t)(NGRP + 1) * NN * 4;
    unsigned short* col_src = (unsigned short*)p; p += (size_t)NGRP * NN * SLOTG * 2;
    unsigned short* ovp     = (unsigned short*)p; p += (size_t)NN * OVS * 2;
    p = (p + 15) & ~(uintptr_t)15;
    unsigned short* Wt      = (unsigned short*)p; p += (size_t)3 * 64 * HID * 2;

    hipMemsetAsync(cnt, 0, (size_t)(NGRP + 1) * NN * sizeof(int), stream);
    k_prep<<<96, 256, 0, stream>>>(Wl, Wr, Wres, Wt);
    k_scat<<<SB, 256, 0, stream>>>(ei, cnt, col_src, ovp);
    k_work<<<GB2, 256, 0, stream>>>(x, Wt, bl, br, xlh, xrh, xresh);
    k_agg<<<AGB, 256, 0, stream>>>(xlh, xrh, xresh, cnt, col_src, ovp,
                                   att, bias, hfeat);
    k_tail<<<NG, 256, 0, stream>>>(hfeat, batch, Wlin, blin,
                                   W1, b1, W2, b2, W3, b3, out);
}

// Round 8
// 217.177 us; speedup vs baseline: 1.0548x; 1.0548x over previous
//
#include <hip/hip_runtime.h>
#include <math.h>

#define NN 50000
#define NE 800000
#define IN_CH 64
#define HEADS 8
#define OC 16
#define HID 128
#define NG 500
#define GB2 ((NN + 63) / 64)        // 782 MFMA-GEMM blocks (64-node tiles)
#define SB 3125                     // scatter blocks: 3125*256 == NE exactly, 1 edge/thread
#define PB 96                       // prep blocks appended to k_scatprep grid
#define NGRP 8                      // XCD-private CSR groups
#define SLOTG 8                     // slots per node per group (deg/XCD ~ Po(2))
#define OVS 64                      // overflow slots per node (device-scope path)
#define XP 72                       // xb LDS pitch (bf16)
#define WP 72                       // wt LDS pitch (bf16)
#define AGB 2048                    // k_agg blocks (multiple of 8 for XCD swizzle)

typedef float v2f __attribute__((ext_vector_type(2)));
typedef _Float16 h2 __attribute__((ext_vector_type(2)));
typedef __attribute__((ext_vector_type(8))) short frag8;   // 8 bf16 (4 VGPRs)
typedef __attribute__((ext_vector_type(4))) float f32x4;   // MFMA C/D

// round-to-nearest-even f32 -> bf16 (as ushort in low bits) — MFMA input path
__device__ __forceinline__ unsigned bf16rn(float f) {
    unsigned u = __float_as_uint(f);
    return (u + 0x7fffu + ((u >> 16) & 1u)) >> 16;
}

// Sum across a 4-lane quad (head = 16 ch = 4 lanes at 4 ch/lane). 4 insts.
__device__ __forceinline__ float dpp4_sum(float x) {
    int t;
    t = __builtin_amdgcn_update_dpp(0, __float_as_int(x), 0xB1, 0xF, 0xF, true);  // quad_perm [1,0,3,2]
    x += __int_as_float(t);
    t = __builtin_amdgcn_update_dpp(0, __float_as_int(x), 0x4E, 0xF, 0xF, true);  // quad_perm [2,3,0,1]
    x += __int_as_float(t);
    return x;
}

// v_dot2_f32_f16 with f32 accumulator (1 inst). Guarded fallback.
#if __has_builtin(__builtin_amdgcn_fdot2)
#define FDOT2A(a, b, c) __builtin_amdgcn_fdot2((a), (b), (c), false)
#else
__device__ __forceinline__ float FDOT2A(h2 a, h2 b, float c) {
    v2f af = __builtin_convertvector(a, v2f);
    v2f bf = __builtin_convertvector(b, v2f);
    return af.x * bf.x + af.y * bf.y + c;
}
#endif

// exp2 (att is pre-scaled by log2e, so logits live in the exp2 domain)
#if __has_builtin(__builtin_amdgcn_exp2f)
#define EXP2(x) __builtin_amdgcn_exp2f(x)
#else
#define EXP2(x) exp2f(x)
#endif

// R28: per-edge math at 4 ch/lane; one wave-inst serves 2 edges (2 nodes/wave).
__device__ __forceinline__ void edge4(uint2 vv, h2 xr01, h2 xr23, h2 a01, h2 a23,
                                      bool pred, float& den,
                                      float& c0, float& c1, float& c2, float& c3) {
    const h2 x01 = __builtin_bit_cast(h2, vv.x);
    const h2 x23 = __builtin_bit_cast(h2, vv.y);
    const h2 t01 = x01 + xr01;
    const h2 t23 = x23 + xr23;
    const h2 e01 = __builtin_elementwise_max(t01, t01 * (_Float16)0.2f);
    const h2 e23 = __builtin_elementwise_max(t23, t23 * (_Float16)0.2f);
    const float q = dpp4_sum(FDOT2A(e23, a23, FDOT2A(e01, a01, 0.f)));
    const float w = EXP2(q);
    if (pred) {
        den += w;
        const v2f f01 = __builtin_convertvector(x01, v2f);
        const v2f f23 = __builtin_convertvector(x23, v2f);
        c0 += w * f01.x; c1 += w * f01.y; c2 += w * f23.x; c3 += w * f23.y;
    }
}

// ---- fused: scatter CSR build (blocks < SB) + W pre-transpose (rest) ------
// XCD-private groups via real XCC_ID (R22); workgroup-scope atomic executes
// in this XCD's L2; overflow -> device-scope spill (always correct).
__global__ __launch_bounds__(256) void k_scatprep(
    const int* __restrict__ ei,
    const float* __restrict__ Wl, const float* __restrict__ Wr,
    const float* __restrict__ Wres, unsigned short* __restrict__ Wt,
    int* __restrict__ cnt,                 // [NGRP+1][NN] (last = overflow, device scope)
    unsigned short* __restrict__ col_src,  // [NGRP][NN][SLOTG]
    unsigned short* __restrict__ ov)       // [NN][OVS]
{
    if (blockIdx.x >= SB) {                // prep blocks: W -> bf16 [mtx][c][k]
        const int i = (blockIdx.x - SB) * 256 + threadIdx.x;
        if (i >= 3 * 64 * HID) return;
        const int m = i >> 13;
        const int r = i & 8191;
        const int k = r >> 7;
        const int c = r & 127;
        const float* W = (m == 0) ? Wl : (m == 1) ? Wr : Wres;
        Wt[(size_t)m * 8192 + c * 64 + k] = (unsigned short)bf16rn(W[k * HID + c]);
        return;
    }
    const int e = blockIdx.x * 256 + threadIdx.x;
    if (e >= NE) return;
    const int s = ei[e];
    const int d = ei[NE + e];
    if ((unsigned)d >= NN) return;                 // defensive
    int xcc;
    asm volatile("s_getreg_b32 %0, hwreg(HW_REG_XCC_ID)" : "=s"(xcc));
    const int g = xcc & (NGRP - 1);
    const int pos = __hip_atomic_fetch_add(&cnt[(size_t)g * NN + d], 1,
                                           __ATOMIC_RELAXED,
                                           __HIP_MEMORY_SCOPE_WORKGROUP);
    if (pos < SLOTG) {
        col_src[((size_t)g * NN + d) * SLOTG + pos] = (unsigned short)s;
    } else {
        const int po = atomicAdd(&cnt[(size_t)NGRP * NN + d], 1);  // device scope
        if (po < OVS)
            ov[(size_t)d * OVS + po] = (unsigned short)s;
    }
}

// ---- R28: one-time compaction — grouped slots + overflow -> csr[n][64]+deg -
// One wave per node; reuses the proven ballot + ds_permute pattern so k_agg
// never pays compaction/overflow logic per node again.
__global__ __launch_bounds__(256) void k_compact(
    const int* __restrict__ cnt, const unsigned short* __restrict__ col_src,
    const unsigned short* __restrict__ ov,
    unsigned short* __restrict__ csr,      // [NN][64]
    int* __restrict__ degv)                // [NN]
{
    const int n = blockIdx.x * 4 + (threadIdx.x >> 6);
    if (n >= NN) return;                               // wave-uniform
    const int lane = threadIdx.x & 63;
    const int grp = lane >> 3;
    const int gsl = lane & 7;
    int cg = cnt[(size_t)grp * NN + n];
    cg = min(max(cg, 0), SLOTG);
    int cov = cnt[(size_t)NGRP * NN + n];
    cov = min(max(cov, 0), OVS);
    const bool valid = gsl < cg;
    int slot = 0;
    if (valid) slot = (int)col_src[((size_t)grp * NN + n) * SLOTG + gsl];
    const unsigned long long mv = __ballot(valid);
    const int cn = __popcll(mv);
    const int pv = __popcll(mv & ((1ull << lane) - 1ull));
    const int dst = valid ? pv : (cn + (lane - pv));
    const int rec = __builtin_amdgcn_ds_permute(dst << 2, slot);
    if (lane < cn) csr[(size_t)n * 64 + lane] = (unsigned short)rec;
    const int take = min(cov, 64 - cn);                // deg max ~35 << 64
    if (lane < take) csr[(size_t)n * 64 + cn + lane] = ov[(size_t)n * OVS + lane];
    if (lane == 0) degv[n] = cn + take;
}

// ---------------- MFMA GEMM only (782 blocks, pure streaming) --------------
__global__ __launch_bounds__(256) void k_work(
    const float* __restrict__ x,
    const unsigned short* __restrict__ Wt,
    const float* __restrict__ bl, const float* __restrict__ br,
    unsigned short* __restrict__ xlh, unsigned short* __restrict__ xrh,
    unsigned short* __restrict__ xresh)
{
    const int tid = threadIdx.x;
    __shared__ short xb[64 * XP];      // [node][k] bf16
    __shared__ short wt[128 * WP];     // [col][k] bf16 (W transposed)
    const int n0 = blockIdx.x * 64;

#pragma unroll
    for (int i = 0; i < 4; ++i) {
        const int idx = i * 256 + tid;
        const int r = idx >> 4;
        const int j4 = idx & 15;
        float4 v = make_float4(0.f, 0.f, 0.f, 0.f);
        if (n0 + r < NN) v = *(const float4*)(x + (size_t)(n0 + r) * IN_CH + j4 * 4);
        uint2 pk;
        pk.x = bf16rn(v.x) | (bf16rn(v.y) << 16);
        pk.y = bf16rn(v.z) | (bf16rn(v.w) << 16);
        *(uint2*)(xb + r * XP + j4 * 4) = pk;
    }

    const int wv = tid >> 6;
    const int lane = tid & 63;
    const int quad = lane >> 4;
    const int mr = lane & 15;
    const int m0 = wv * 16;

    for (int mtx = 0; mtx < 3; ++mtx) {
        const unsigned short* __restrict__ Wtm = Wt + (size_t)mtx * 8192;
        unsigned short* __restrict__ outp = (mtx == 0) ? xlh : (mtx == 1) ? xrh : xresh;

        __syncthreads();
#pragma unroll
        for (int i = 0; i < 4; ++i) {
            const int idx = i * 256 + tid;
            const int c = idx >> 3;
            const int k0 = (idx & 7) * 8;
            const uint4 v = *(const uint4*)(Wtm + c * 64 + k0);
            *(uint4*)(wt + c * WP + k0) = v;
        }
        __syncthreads();

        const frag8 a0 = *(const frag8*)(xb + (m0 + mr) * XP + quad * 8);
        const frag8 a1 = *(const frag8*)(xb + (m0 + mr) * XP + 32 + quad * 8);

#pragma unroll
        for (int nt = 0; nt < 8; ++nt) {
            const int c = nt * 16 + mr;
            const frag8 b0 = *(const frag8*)(wt + c * WP + quad * 8);
            const frag8 b1 = *(const frag8*)(wt + c * WP + 32 + quad * 8);
            f32x4 acc = {0.f, 0.f, 0.f, 0.f};
            acc = __builtin_amdgcn_mfma_f32_16x16x32_bf16(a0, b0, acc, 0, 0, 0);
            acc = __builtin_amdgcn_mfma_f32_16x16x32_bf16(a1, b1, acc, 0, 0, 0);

            const float bv = (mtx == 0) ? bl[c] : (mtx == 1) ? br[c] : 0.f;
            const int node_base = n0 + m0 + quad * 4;
#pragma unroll
            for (int r = 0; r < 4; ++r) {
                const int node = node_base + r;
                if (node < NN) {
                    const _Float16 hv = (_Float16)(acc[r] + bv);
                    outp[(size_t)node * HID + c] = __builtin_bit_cast(unsigned short, hv);
                }
            }
        }
    }
}

// ---- Fused attention v2: 2 nodes per wave, 4 ch/lane ----------------------
// lanes 0-31 -> node 2p, lanes 32-63 -> node 2p+1. Head = 16 ch = 4 lanes ->
// 4-inst quad reduction. Slot indices are per-lane 2B loads from the node's
// L1-hot csr row (no readlane/ballot/permute). Single predicated batch path.
// att pre-scaled by log2e -> EXP2 direct. Channel base for lane = (ll*4).
__global__ __launch_bounds__(256) void k_agg(
    const unsigned short* __restrict__ xlh, const unsigned short* __restrict__ xrh,
    const unsigned short* __restrict__ xresh,
    const int* __restrict__ degv, const unsigned short* __restrict__ csr,
    const float* __restrict__ att, const float* __restrict__ bias,
    float* __restrict__ hfeat)
{
    const int lane = threadIdx.x & 63;
    const int ll = lane & 31;
    const int half = lane >> 5;
    const int bid = blockIdx.x;
    const int swzb = (bid & 7) * (AGB / 8) + (bid >> 3);
    const int wid = __builtin_amdgcn_readfirstlane((swzb * 256 + (int)threadIdx.x) >> 6);
    const int nwav = (AGB * 256) >> 6;                // 8192
    const int NP = NN / 2;                            // 25000 pairs
    const int qq = NP / nwav;
    const int rr = NP % nwav;
    const int pbeg = wid * qq + (wid < rr ? wid : rr);
    const int pend = pbeg + qq + (wid < rr ? 1 : 0);

    // lane's 4 channels = [ll*4, ll*4+4) = head (ll>>2), ch ((ll&3)*4)
    const float4 a4 = *((const float4*)att + ll);
    h2 a01, a23;
    a01.x = (_Float16)(a4.x * 1.44269504f);           // fold log2e into att
    a01.y = (_Float16)(a4.y * 1.44269504f);
    a23.x = (_Float16)(a4.z * 1.44269504f);
    a23.y = (_Float16)(a4.w * 1.44269504f);
    const float4 b4 = *((const float4*)bias + ll);

    for (int p = pbeg; p < pend; ++p) {
        const int n = 2 * p + half;
        // issue all setup loads first (no deg dependency for slots)
        const uint2 vr = *((const uint2*)(xrh + (size_t)n * HID) + ll);
        const uint2 vn = *((const uint2*)(xlh + (size_t)n * HID) + ll);
        const uint2 vs = *((const uint2*)(xresh + (size_t)n * HID) + ll);
        int S[8]; uint2 VA[8], VB[8];
#pragma unroll
        for (int u = 0; u < 8; ++u) S[u] = (int)csr[(size_t)n * 64 + u];
        int deg = degv[n];
        deg = min(max(deg, 0), 64);
        // gathers batch 0 (garbage slots bounded; results predicated off)
#pragma unroll
        for (int u = 0; u < 8; ++u) {
            int s = S[u]; if ((unsigned)s >= NN) s = 0;
            VA[u] = *((const uint2*)(xlh + (size_t)s * HID) + ll);
        }

        // self-loop (hides batch-0 gather latency)
        const h2 xr01 = __builtin_bit_cast(h2, vr.x);
        const h2 xr23 = __builtin_bit_cast(h2, vr.y);
        const h2 xl01 = __builtin_bit_cast(h2, vn.x);
        const h2 xl23 = __builtin_bit_cast(h2, vn.y);
        const h2 t01 = xl01 + xr01;
        const h2 t23 = xl23 + xr23;
        const h2 e01 = __builtin_elementwise_max(t01, t01 * (_Float16)0.2f);
        const h2 e23 = __builtin_elementwise_max(t23, t23 * (_Float16)0.2f);
        const float qs = dpp4_sum(FDOT2A(e23, a23, FDOT2A(e01, a01, 0.f)));
        float den = EXP2(qs);
        const v2f f01 = __builtin_convertvector(xl01, v2f);
        const v2f f23 = __builtin_convertvector(xl23, v2f);
        float c0 = den * f01.x, c1 = den * f01.y, c2 = den * f23.x, c3 = den * f23.y;

        const int degA = __builtin_amdgcn_readlane(deg, 0);
        const int degB = __builtin_amdgcn_readlane(deg, 32);
        const int nb = (max(degA, degB) + 7) >> 3;    // wave-uniform

        int b = 0;
        for (; b + 2 <= nb; b += 2) {
#pragma unroll
            for (int u = 0; u < 8; ++u) S[u] = (int)csr[(size_t)n * 64 + (b + 1) * 8 + u];
#pragma unroll
            for (int u = 0; u < 8; ++u)
                edge4(VA[u], xr01, xr23, a01, a23, b * 8 + u < deg, den, c0, c1, c2, c3);
#pragma unroll
            for (int u = 0; u < 8; ++u) {              // gathers b+1 (waits S)
                int s = S[u]; if ((unsigned)s >= NN) s = 0;
                VB[u] = *((const uint2*)(xlh + (size_t)s * HID) + ll);
            }
            if (b + 2 < nb) {
#pragma unroll
                for (int u = 0; u < 8; ++u) S[u] = (int)csr[(size_t)n * 64 + (b + 2) * 8 + u];
            }
#pragma unroll
            for (int u = 0; u < 8; ++u)
                edge4(VB[u], xr01, xr23, a01, a23, (b + 1) * 8 + u < deg, den, c0, c1, c2, c3);
            if (b + 2 < nb) {
#pragma unroll
                for (int u = 0; u < 8; ++u) {          // gathers b+2
                    int s = S[u]; if ((unsigned)s >= NN) s = 0;
                    VA[u] = *((const uint2*)(xlh + (size_t)s * HID) + ll);
                }
            }
        }
        if (b < nb) {                                  // last odd batch (in VA)
#pragma unroll
            for (int u = 0; u < 8; ++u)
                edge4(VA[u], xr01, xr23, a01, a23, b * 8 + u < deg, den, c0, c1, c2, c3);
        }

        const float inv = 1.f / den;
        const v2f s01 = __builtin_convertvector(__builtin_bit_cast(h2, vs.x), v2f);
        const v2f s23 = __builtin_convertvector(__builtin_bit_cast(h2, vs.y), v2f);
        float4 o;
        o.x = c0 * inv + s01.x + b4.x;
        o.y = c1 * inv + s01.y + b4.y;
        o.z = c2 * inv + s23.x + b4.z;
        o.w = c3 * inv + s23.y + b4.w;
        *((float4*)(hfeat + (size_t)n * HID) + ll) = o;
    }
}

// ---- Fused tail: per-graph {Wlin+ELU pool} + MLP ---------------------------
__global__ __launch_bounds__(256) void k_tail(
    const float* __restrict__ hfeat, const int* __restrict__ batch,
    const float* __restrict__ Wlin, const float* __restrict__ blin,
    const float* __restrict__ W1, const float* __restrict__ b1,
    const float* __restrict__ W2, const float* __restrict__ b2,
    const float* __restrict__ W3, const float* __restrict__ b3,
    float* __restrict__ out)
{
    __shared__ float sWlin[HID * 16];
    __shared__ float sblin[16];
    __shared__ float sW1[256], sb1[16], sW2[512], sb2[32], sW3[160], sb3[5];
    __shared__ float red[256][17];
    __shared__ float sg[16], sv1[16], sv2[32];
    const int g = blockIdx.x;
    const int tid = threadIdx.x;

    for (int i = tid; i < HID * 16; i += 256) sWlin[i] = Wlin[i];
    if (tid < 16)  sblin[tid] = blin[tid];
    if (tid < 256) sW1[tid] = W1[tid];
    for (int i = tid; i < 512; i += 256) sW2[i] = W2[i];
    if (tid < 160) sW3[tid] = W3[tid];
    if (tid < 16)  sb1[tid] = b1[tid];
    if (tid < 32)  sb2[tid] = b2[tid];
    if (tid < 5)   sb3[tid] = b3[tid];
    __syncthreads();

    int lo = 0, hi = NN;
    while (lo < hi) { int mid = (lo + hi) >> 1; if (batch[mid] < g) lo = mid + 1; else hi = mid; }
    int lo2 = lo, hi2 = NN;
    while (lo2 < hi2) { int mid = (lo2 + hi2) >> 1; if (batch[mid] < g + 1) lo2 = mid + 1; else hi2 = mid; }
    const int nbeg = lo, nend = lo2;

    float sum16[16];
#pragma unroll
    for (int j = 0; j < 16; ++j) sum16[j] = 0.f;

    for (int n = nbeg + tid; n < nend; n += 256) {
        float acc[16];
#pragma unroll
        for (int j = 0; j < 16; ++j) acc[j] = sblin[j];
        const float4* hrow = (const float4*)(hfeat + (size_t)n * HID);
#pragma unroll 8
        for (int kc = 0; kc < 32; ++kc) {
            const float4 v = hrow[kc];
#pragma unroll
            for (int j = 0; j < 16; ++j) {
                acc[j] += v.x * sWlin[(kc * 4 + 0) * 16 + j] + v.y * sWlin[(kc * 4 + 1) * 16 + j]
                        + v.z * sWlin[(kc * 4 + 2) * 16 + j] + v.w * sWlin[(kc * 4 + 3) * 16 + j];
            }
        }
#pragma unroll
        for (int j = 0; j < 16; ++j) {
            float o = acc[j];
            o = o > 0.f ? o : __expf(o) - 1.f;
            sum16[j] += o;
        }
    }

#pragma unroll
    for (int j = 0; j < 16; ++j) red[tid][j] = sum16[j];
    __syncthreads();
    for (int s = 128; s > 0; s >>= 1) {
        if (tid < s) {
#pragma unroll
            for (int j = 0; j < 16; ++j) red[tid][j] += red[tid + s][j];
        }
        __syncthreads();
    }

    if (tid < 16) sg[tid] = red[0][tid] / fmaxf((float)(nend - nbeg), 1.f);
    __syncthreads();
    if (tid < 16) {
        float s = sb1[tid];
#pragma unroll
        for (int c = 0; c < 16; ++c) s += sg[c] * sW1[c * 16 + tid];
        sv1[tid] = fmaxf(s, 0.f);
    }
    __syncthreads();
    if (tid < 32) {
        float s = sb2[tid];
#pragma unroll
        for (int c = 0; c < 16; ++c) s += sv1[c] * sW2[c * 32 + tid];
        sv2[tid] = fmaxf(s, 0.f);
    }
    __syncthreads();
    if (tid < 5) {
        float s = sb3[tid];
#pragma unroll
        for (int c = 0; c < 32; ++c) s += sv2[c] * sW3[c * 5 + tid];
        out[g * 5 + tid] = s;
    }
}

extern "C" void kernel_launch(void* const* d_in, const int* in_sizes, int n_in,
                              void* d_out, int out_size, void* d_ws, size_t ws_size,
                              hipStream_t stream)
{
    const float* x    = (const float*)d_in[0];
    const int*   ei   = (const int*)d_in[1];
    const int*   batch= (const int*)d_in[2];
    const float* Wl   = (const float*)d_in[3];
    const float* bl   = (const float*)d_in[4];
    const float* Wr   = (const float*)d_in[5];
    const float* br   = (const float*)d_in[6];
    const float* att  = (const float*)d_in[7];
    const float* Wres = (const float*)d_in[8];
    const float* bias = (const float*)d_in[9];
    const float* Wlin = (const float*)d_in[10];
    const float* blin = (const float*)d_in[11];
    const float* W1   = (const float*)d_in[12];
    const float* b1   = (const float*)d_in[13];
    const float* W2   = (const float*)d_in[14];
    const float* b2   = (const float*)d_in[15];
    const float* W3   = (const float*)d_in[16];
    const float* b3   = (const float*)d_in[17];
    float* out = (float*)d_out;

    uintptr_t p = (uintptr_t)d_ws;
    unsigned short* xlh   = (unsigned short*)p; p += (size_t)NN * HID * 2;
    unsigned short* xrh   = (unsigned short*)p; p += (size_t)NN * HID * 2;
    unsigned short* xresh = (unsigned short*)p; p += (size_t)NN * HID * 2;
    p = (p + 15) & ~(uintptr_t)15;
    float* hfeat  = (float*)p; p += (size_t)NN * HID * 4;
    int* cnt      = (int*)p;   p += (size_t)(NGRP + 1) * NN * 4;
    unsigned short* col_src = (unsigned short*)p; p += (size_t)NGRP * NN * SLOTG * 2;
    unsigned short* ovp     = (unsigned short*)p; p += (size_t)NN * OVS * 2;
    p = (p + 15) & ~(uintptr_t)15;
    unsigned short* csr     = (unsigned short*)p; p += (size_t)NN * 64 * 2;
    int* degv               = (int*)p;            p += (size_t)NN * 4;
    p = (p + 15) & ~(uintptr_t)15;
    unsigned short* Wt      = (unsigned short*)p; p += (size_t)3 * 64 * HID * 2;

    hipMemsetAsync(cnt, 0, (size_t)(NGRP + 1) * NN * sizeof(int), stream);
    k_scatprep<<<SB + PB, 256, 0, stream>>>(ei, Wl, Wr, Wres, Wt, cnt, col_src, ovp);
    k_compact<<<(NN + 3) / 4, 256, 0, stream>>>(cnt, col_src, ovp, csr, degv);
    k_work<<<GB2, 256, 0, stream>>>(x, Wt, bl, br, xlh, xrh, xresh);
    k_agg<<<AGB, 256, 0, stream>>>(xlh, xrh, xresh, degv, csr, att, bias, hfeat);
    k_tail<<<NG, 256, 0, stream>>>(hfeat, batch, Wlin, blin,
                                   W1, b1, W2, b2, W3, b3, out);
}